// Round 9
// baseline (52.581 us; speedup 1.0000x reference)
//
#include <hip/hip_runtime.h>

// Shapes fixed by the benchmark's setup_inputs().
constexpr int T_DIM       = 16;
constexpr int TOK         = 16384;
constexpr int E_DIM       = 128;
constexpr int N_NODE_C    = 8192;
constexpr int NUM_NODES_C = 50000;
constexpr int COMP_LEN_C  = 64;
constexpr int MAX_LEN_C   = 782;
constexpr int COMP_DIM_C  = 32;
constexpr float EPS_F     = 1e-5f;

constexpr int PER_T       = 32;                       // workgroups per t (512 total, 2/CU)
constexpr int ROWS_PER_WG = N_NODE_C / PER_T;         // 256 rows; 32/wave (8 waves); 8 quads/wave
constexpr int D2          = COMP_LEN_C * COMP_DIM_C;  // 2048

// d_ws layout: W8 (3.2MB, zeroed each call) | P partials (4MB, fully overwritten)
constexpr size_t W8_BYTES = (size_t)NUM_NODES_C * COMP_LEN_C;   // 3,200,000
constexpr size_t P_OFF    = 3211264;                            // 4KB-aligned
// P: [T_DIM][PER_T][D2] floats = 16*32*2048*4 = 4 MB (L2-resident)

// --- Build W[n][c] (uint8 counts, 50000x64) via byte-atomics into u32 words.
// Counts ~Binomial(782, 1/50000) -> max ~3, no byte overflow. 256 WGs (c x j-chunk).
__global__ void build_w8_kernel(const int* __restrict__ sidx, unsigned* __restrict__ W8w) {
  const int c  = blockIdx.x >> 2;          // 64 c-values
  const int jc = blockIdx.x & 3;           // 4 j-chunks
  const int j  = jc * 196 + threadIdx.x;   // 4*196 = 784 >= 782
  if (j < MAX_LEN_C && threadIdx.x < 196) {
    int n = sidx[c * MAX_LEN_C + j];
    int byteoff = n * COMP_LEN_C + c;
    atomicAdd(&W8w[byteoff >> 2], 1u << (8 * (byteoff & 3)));
  }
}

// --- Fused: LN1 + pool-of-4 + sparse LDS scatter; flush via ONE float4 store/thread.
// 512 threads = 8 waves; each wave: 32 rows as 8 quads, 16 lanes/row, 8 elems/lane
// (pool sums lane-local). x loads unconditional+upfront, independent of the
// nit->W32->ballot chain; W only gates compute+scatter (~37% dead rows skip VALU).
// NO global atomics anywhere.
__global__ __launch_bounds__(512) void fused_ln_scatter(
    const float* __restrict__ x, const float* __restrict__ g1, const float* __restrict__ b1,
    const int* __restrict__ node_idx, const unsigned* __restrict__ W32,
    float* __restrict__ P) {
  __shared__ float sagg[D2];  // 8 KB
  const int t     = blockIdx.x / PER_T;
  const int chunk = blockIdx.x % PER_T;
  const int lane  = threadIdx.x & 63;
  const int wave  = threadIdx.x >> 6;   // 8 waves
  const int sub   = lane >> 4;          // row within quad
  const int sl    = lane & 15;          // 16 lanes per row

  // vectorized LDS zero: 2048 floats / 512 threads = one float4 each
  reinterpret_cast<float4*>(sagg)[threadIdx.x] = make_float4(0.f, 0.f, 0.f, 0.f);
  __syncthreads();

  const float* xt  = x + (size_t)t * TOK * E_DIM;
  const int*   nit = node_idx + (size_t)t * N_NODE_C;
  const int d0 = sl * 2, d1 = sl * 2 + 1;
  const int rowbase = chunk * ROWS_PER_WG + wave * 32;

  // Chain 1: unconditional x loads for all 8 quads (16 float4s in flight).
  float4 xa[8], xb[8];
#pragma unroll
  for (int q = 0; q < 8; ++q) {
    const float* xr = xt + (size_t)(rowbase + q * 4 + sub) * E_DIM + sl * 8;
    xa[q] = *reinterpret_cast<const float4*>(xr);
    xb[q] = *reinterpret_cast<const float4*>(xr + 4);
  }
  // Chain 2 (independent): node ids -> W words -> aliveness ballots.
  int nrow[8];
#pragma unroll
  for (int q = 0; q < 8; ++q) nrow[q] = nit[rowbase + q * 4 + sub];
  unsigned cw[8];
#pragma unroll
  for (int q = 0; q < 8; ++q) cw[q] = W32[(size_t)nrow[q] * 16 + sl];
  unsigned msq[8];
#pragma unroll
  for (int q = 0; q < 8; ++q) {
    unsigned long long b = __ballot(cw[q] != 0);
    msq[q] = (unsigned)((b >> (sub * 16)) & 0xFFFFull);  // uniform within 16-lane subgroup
  }

  // per-lane gains for elems [sl*8, sl*8+8); biases enter only as 4-group sums
  const float4 g0  = *reinterpret_cast<const float4*>(g1 + sl * 8);
  const float4 g4  = *reinterpret_cast<const float4*>(g1 + sl * 8 + 4);
  const float4 t0  = *reinterpret_cast<const float4*>(b1 + sl * 8);
  const float4 t4  = *reinterpret_cast<const float4*>(b1 + sl * 8 + 4);
  const float bs0 = t0.x + t0.y + t0.z + t0.w;
  const float bs1 = t4.x + t4.y + t4.z + t4.w;

#pragma unroll
  for (int q = 0; q < 8; ++q) {
    if (msq[q]) {  // dead rows skip compute+scatter; loads already issued
      const float4 a = xa[q], c4 = xb[q];
      float s  = (a.x + a.y) + (a.z + a.w) + (c4.x + c4.y) + (c4.z + c4.w);
      float ss = a.x * a.x + a.y * a.y + a.z * a.z + a.w * a.w
               + c4.x * c4.x + c4.y * c4.y + c4.z * c4.z + c4.w * c4.w;
#pragma unroll
      for (int m = 1; m < 16; m <<= 1) { s += __shfl_xor(s, m); ss += __shfl_xor(ss, m); }
      float mu   = s * (1.0f / E_DIM);
      float var  = ss * (1.0f / E_DIM) - mu * mu;
      float rstd = rsqrtf(var + EPS_F);
      float q0 = ((a.x - mu) * g0.x + (a.y - mu) * g0.y + (a.z - mu) * g0.z + (a.w - mu) * g0.w) * rstd + bs0;
      float q1 = ((c4.x - mu) * g4.x + (c4.y - mu) * g4.y + (c4.z - mu) * g4.z + (c4.w - mu) * g4.w) * rstd + bs1;

      unsigned ms = msq[q];
      while (ms) {
        int j = __builtin_ctz(ms); ms &= ms - 1;
        unsigned w4 = (unsigned)__shfl((int)cw[q], sub * 16 + j);
        int cb = j * 4;
#pragma unroll
        for (int byte = 0; byte < 4; ++byte) {
          unsigned w = (w4 >> (8 * byte)) & 0xFFu;
          if (w) {  // uniform within the 16-lane subgroup
            float fw = (float)w;
            atomicAdd(&sagg[(cb + byte) * COMP_DIM_C + d0], q0 * fw);
            atomicAdd(&sagg[(cb + byte) * COMP_DIM_C + d1], q1 * fw);
          }
        }
      }
    }
  }

  __syncthreads();
  // Flush: one coalesced float4 store per thread into this WG's partial row.
  float* pr = P + ((size_t)t * PER_T + chunk) * D2;
  reinterpret_cast<float4*>(pr)[threadIdx.x] =
      reinterpret_cast<const float4*>(sagg)[threadIdx.x];
}

// --- Per t: sum 32 partials (4MB total, L2-resident), scale, LN with ln2_g/b.
__global__ __launch_bounds__(256) void final_ln_kernel(
    const float* __restrict__ P, const float* __restrict__ g2,
    const float* __restrict__ b2, float* __restrict__ out) {
  const float scale = 1.0f / (4.0f * (float)MAX_LEN_C);
  __shared__ float red[16];
  const int t   = blockIdx.x;
  const int tid = threadIdx.x;

  float acc[8];
#pragma unroll
  for (int k = 0; k < 8; ++k) acc[k] = 0.0f;
  const float* base = P + (size_t)t * PER_T * D2 + tid * 8;
  for (int p = 0; p < PER_T; ++p) {
    float4 v0 = *reinterpret_cast<const float4*>(base + (size_t)p * D2);
    float4 v1 = *reinterpret_cast<const float4*>(base + (size_t)p * D2 + 4);
    acc[0] += v0.x; acc[1] += v0.y; acc[2] += v0.z; acc[3] += v0.w;
    acc[4] += v1.x; acc[5] += v1.y; acc[6] += v1.z; acc[7] += v1.w;
  }
  float y[8];
  float s = 0.0f, ss = 0.0f;
#pragma unroll
  for (int k = 0; k < 8; ++k) {
    float v = acc[k] * scale;
    y[k] = v; s += v; ss += v * v;
  }
#pragma unroll
  for (int m = 1; m < 64; m <<= 1) { s += __shfl_xor(s, m); ss += __shfl_xor(ss, m); }
  const int w = tid >> 6, ln = tid & 63;
  if (ln == 0) { red[w] = s; red[8 + w] = ss; }
  __syncthreads();
  float ts  = red[0] + red[1] + red[2] + red[3];
  float tss = red[8] + red[9] + red[10] + red[11];
  float mu   = ts * (1.0f / D2);
  float var  = tss * (1.0f / D2) - mu * mu;
  float rstd = rsqrtf(var + EPS_F);
#pragma unroll
  for (int k = 0; k < 8; ++k) {
    int idx = tid * 8 + k;
    out[(size_t)t * D2 + idx] = (y[k] - mu) * rstd * g2[idx] + b2[idx];
  }
}

extern "C" void kernel_launch(void* const* d_in, const int* in_sizes, int n_in,
                              void* d_out, int out_size, void* d_ws, size_t ws_size,
                              hipStream_t stream) {
  const float* x     = (const float*)d_in[0];
  const float* ln1_g = (const float*)d_in[1];
  const float* ln1_b = (const float*)d_in[2];
  const float* ln2_g = (const float*)d_in[3];
  const float* ln2_b = (const float*)d_in[4];
  const int* node_idx = (const int*)d_in[5];
  const int* sidx     = (const int*)d_in[6];
  float* out = (float*)d_out;

  unsigned char* ws = (unsigned char*)d_ws;
  unsigned char* W8 = ws;
  float* P = (float*)(ws + P_OFF);   // 4 MB, fully overwritten each call

  hipMemsetAsync(W8, 0, W8_BYTES, stream);
  build_w8_kernel<<<COMP_LEN_C * 4, 256, 0, stream>>>(sidx, (unsigned*)W8);
  fused_ln_scatter<<<T_DIM * PER_T, 512, 0, stream>>>(x, ln1_g, ln1_b, node_idx,
                                                      (const unsigned*)W8, P);
  final_ln_kernel<<<T_DIM, 256, 0, stream>>>(P, ln2_g, ln2_b, out);
}

// Round 11
// 48.677 us; speedup vs baseline: 1.0802x; 1.0802x over previous
//
#include <hip/hip_runtime.h>
#include <hip/hip_cooperative_groups.h>

namespace cg = cooperative_groups;

// Shapes fixed by the benchmark's setup_inputs().
constexpr int T_DIM       = 16;
constexpr int TOK         = 16384;
constexpr int E_DIM       = 128;
constexpr int N_NODE_C    = 8192;
constexpr int NUM_NODES_C = 50000;
constexpr int COMP_LEN_C  = 64;
constexpr int MAX_LEN_C   = 782;
constexpr int COMP_DIM_C  = 32;
constexpr float EPS_F     = 1e-5f;

constexpr int GRID_C      = 512;   // coop grid: 2 blocks/CU needed, >=4 available
constexpr int BLK_C       = 256;   // 4 waves
constexpr int PER_T       = 32;    // blocks per t in phase 2
constexpr int ROWS_PER_WG = N_NODE_C / PER_T;          // 256 rows/WG; 64/wave
constexpr int D2          = COMP_LEN_C * COMP_DIM_C;   // 2048
constexpr int W_WORDS     = NUM_NODES_C * COMP_LEN_C / 4;  // 800,000 u32

// d_ws layout: W8 (3.2MB) | Agg (128KB, fallback only) | P (4MB, coop only)
constexpr size_t W8_BYTES  = (size_t)NUM_NODES_C * COMP_LEN_C;    // 3,200,000
constexpr size_t AGG_OFF   = 3211264;
constexpr size_t AGG_BYTES = (size_t)T_DIM * D2 * sizeof(float);  // 131,072
constexpr size_t ZERO_BYTES = AGG_OFF + AGG_BYTES;                // fallback memset
constexpr size_t P_OFF     = 3407872;                             // 4MB partials

// ---------------- shared device helpers (LN1+scatter inner body) ----------------
// Processes 4 quads (16 rows) for one wave: 16 lanes/row, 8 elems/lane.
// Returns nothing; accumulates into sagg via LDS atomics.
__device__ __forceinline__ void ln_scatter_batch(
    const float* __restrict__ xt, const int* __restrict__ nit,
    const unsigned* __restrict__ W32, float* __restrict__ sagg,
    int rowbase, int qb, int sub, int sl,
    const float4& g0, const float4& g4, float bs0, float bs1, int d0, int d1) {
  float4 xa[4], xb4[4];
#pragma unroll
  for (int q = 0; q < 4; ++q) {
    const float* xr = xt + (size_t)(rowbase + (qb + q) * 4 + sub) * E_DIM + sl * 8;
    xa[q]  = *reinterpret_cast<const float4*>(xr);
    xb4[q] = *reinterpret_cast<const float4*>(xr + 4);
  }
  int nrow[4];
#pragma unroll
  for (int q = 0; q < 4; ++q) nrow[q] = nit[rowbase + (qb + q) * 4 + sub];
  unsigned cw[4];
#pragma unroll
  for (int q = 0; q < 4; ++q) cw[q] = W32[(size_t)nrow[q] * 16 + sl];
  unsigned msq[4];
#pragma unroll
  for (int q = 0; q < 4; ++q) {
    unsigned long long bl = __ballot(cw[q] != 0);
    msq[q] = (unsigned)((bl >> (sub * 16)) & 0xFFFFull);
  }
#pragma unroll
  for (int q = 0; q < 4; ++q) {
    if (msq[q]) {  // dead rows (~37%) skip compute+scatter
      const float4 a = xa[q], c4 = xb4[q];
      float s  = (a.x + a.y) + (a.z + a.w) + (c4.x + c4.y) + (c4.z + c4.w);
      float ss = a.x * a.x + a.y * a.y + a.z * a.z + a.w * a.w
               + c4.x * c4.x + c4.y * c4.y + c4.z * c4.z + c4.w * c4.w;
#pragma unroll
      for (int m = 1; m < 16; m <<= 1) { s += __shfl_xor(s, m); ss += __shfl_xor(ss, m); }
      float mu   = s * (1.0f / E_DIM);
      float var  = ss * (1.0f / E_DIM) - mu * mu;
      float rstd = rsqrtf(var + EPS_F);
      float q0 = ((a.x - mu) * g0.x + (a.y - mu) * g0.y + (a.z - mu) * g0.z + (a.w - mu) * g0.w) * rstd + bs0;
      float q1 = ((c4.x - mu) * g4.x + (c4.y - mu) * g4.y + (c4.z - mu) * g4.z + (c4.w - mu) * g4.w) * rstd + bs1;
      unsigned ms = msq[q];
      while (ms) {
        int j = __builtin_ctz(ms); ms &= ms - 1;
        unsigned w4 = (unsigned)__shfl((int)cw[q], sub * 16 + j);
        int cb = j * 4;
#pragma unroll
      for (int byte = 0; byte < 4; ++byte) {
          unsigned w = (w4 >> (8 * byte)) & 0xFFu;
          if (w) {
            float fw = (float)w;
            atomicAdd(&sagg[(cb + byte) * COMP_DIM_C + d0], q0 * fw);
            atomicAdd(&sagg[(cb + byte) * COMP_DIM_C + d1], q1 * fw);
          }
        }
      }
    }
  }
}

// ---------------- cooperative mega-kernel ----------------
__global__ __launch_bounds__(256, 4) void mega_kernel(
    const float* __restrict__ x, const float* __restrict__ g1, const float* __restrict__ b1,
    const int* __restrict__ node_idx, const int* __restrict__ sidx,
    const float* __restrict__ g2, const float* __restrict__ b2,
    unsigned* __restrict__ W8w, float* __restrict__ P, float* __restrict__ out) {
  cg::grid_group grid = cg::this_grid();
  __shared__ float sagg[D2];  // 8 KB; reused as scratch in phase 3
  const int gtid = blockIdx.x * BLK_C + threadIdx.x;  // 131072 threads

  // Phase 0: zero W table.
  for (int i = gtid; i < W_WORDS; i += GRID_C * BLK_C) W8w[i] = 0u;
  grid.sync();

  // Phase 1: build W counts (50048 entries, one per thread).
  if (gtid < COMP_LEN_C * MAX_LEN_C) {
    int c = gtid / MAX_LEN_C;
    int n = sidx[gtid];
    int byteoff = n * COMP_LEN_C + c;
    atomicAdd(&W8w[byteoff >> 2], 1u << (8 * (byteoff & 3)));
  }
  grid.sync();

  // Phase 2: LN1 + pool + scatter; flush per-WG partials to P.
  {
    const unsigned* W32 = (const unsigned*)W8w;
    const int t     = blockIdx.x >> 5;
    const int chunk = blockIdx.x & 31;
    const int lane  = threadIdx.x & 63;
    const int wave  = threadIdx.x >> 6;   // 4 waves
    const int sub   = lane >> 4;
    const int sl    = lane & 15;

#pragma unroll
    for (int u = 0; u < 2; ++u)
      reinterpret_cast<float4*>(sagg)[threadIdx.x + u * 256] = make_float4(0.f, 0.f, 0.f, 0.f);
    __syncthreads();

    const float4 g0  = *reinterpret_cast<const float4*>(g1 + sl * 8);
    const float4 g4  = *reinterpret_cast<const float4*>(g1 + sl * 8 + 4);
    const float4 t0  = *reinterpret_cast<const float4*>(b1 + sl * 8);
    const float4 t4  = *reinterpret_cast<const float4*>(b1 + sl * 8 + 4);
    const float bs0 = t0.x + t0.y + t0.z + t0.w;
    const float bs1 = t4.x + t4.y + t4.z + t4.w;

    const float* xt  = x + (size_t)t * TOK * E_DIM;
    const int*   nit = node_idx + (size_t)t * N_NODE_C;
    const int d0 = sl * 2, d1 = sl * 2 + 1;
    const int rowbase = chunk * ROWS_PER_WG + wave * 64;  // 64 rows per wave

#pragma unroll
    for (int b = 0; b < 4; ++b)
      ln_scatter_batch(xt, nit, W32, sagg, rowbase, b * 4, sub, sl, g0, g4, bs0, bs1, d0, d1);

    __syncthreads();
    float* pr = P + ((size_t)t * PER_T + chunk) * D2;
#pragma unroll
    for (int u = 0; u < 2; ++u)
      reinterpret_cast<float4*>(pr)[threadIdx.x + u * 256] =
          reinterpret_cast<const float4*>(sagg)[threadIdx.x + u * 256];
  }
  grid.sync();

  // Phase 3: final LN per t (16 blocks; 256 threads x 8 elems).
  if (blockIdx.x < T_DIM) {
    const float scale = 1.0f / (4.0f * (float)MAX_LEN_C);
    const int t3  = blockIdx.x;
    const int tid = threadIdx.x;
    float acc[8] = {0.f,0.f,0.f,0.f,0.f,0.f,0.f,0.f};
    const float* base = P + (size_t)t3 * PER_T * D2 + tid * 8;
    for (int p = 0; p < PER_T; ++p) {
      float4 v0 = *reinterpret_cast<const float4*>(base + (size_t)p * D2);
      float4 v1 = *reinterpret_cast<const float4*>(base + (size_t)p * D2 + 4);
      acc[0]+=v0.x; acc[1]+=v0.y; acc[2]+=v0.z; acc[3]+=v0.w;
      acc[4]+=v1.x; acc[5]+=v1.y; acc[6]+=v1.z; acc[7]+=v1.w;
    }
    float y[8];
    float s = 0.f, ss = 0.f;
#pragma unroll
    for (int k = 0; k < 8; ++k) { float v = acc[k] * scale; y[k] = v; s += v; ss += v * v; }
#pragma unroll
    for (int m = 1; m < 64; m <<= 1) { s += __shfl_xor(s, m); ss += __shfl_xor(ss, m); }
    const int wv = tid >> 6, ln = tid & 63;
    if (ln == 0) { sagg[wv] = s; sagg[8 + wv] = ss; }
    __syncthreads();
    float ts  = sagg[0] + sagg[1] + sagg[2] + sagg[3];
    float tss = sagg[8] + sagg[9] + sagg[10] + sagg[11];
    float mu   = ts * (1.0f / D2);
    float var  = tss * (1.0f / D2) - mu * mu;
    float rstd = rsqrtf(var + EPS_F);
#pragma unroll
    for (int k = 0; k < 8; ++k) {
      int idx = tid * 8 + k;
      out[(size_t)t3 * D2 + idx] = (y[k] - mu) * rstd * g2[idx] + b2[idx];
    }
  }
}

// ---------------- fallback path (R8-proven, 49.7 us) ----------------
__global__ void build_w8_kernel(const int* __restrict__ sidx, unsigned* __restrict__ W8w) {
  const int c  = blockIdx.x >> 2;
  const int jc = blockIdx.x & 3;
  const int j  = jc * 196 + threadIdx.x;
  if (j < MAX_LEN_C && threadIdx.x < 196) {
    int n = sidx[c * MAX_LEN_C + j];
    int byteoff = n * COMP_LEN_C + c;
    atomicAdd(&W8w[byteoff >> 2], 1u << (8 * (byteoff & 3)));
  }
}

__global__ __launch_bounds__(256) void fused_ln_scatter_fb(
    const float* __restrict__ x, const float* __restrict__ g1, const float* __restrict__ b1,
    const int* __restrict__ node_idx, const unsigned* __restrict__ W32,
    float* __restrict__ Agg) {
  __shared__ float sagg[D2];
  const int t     = blockIdx.x >> 6;        // PER_T_FB = 64
  const int chunk = blockIdx.x & 63;
  const int lane  = threadIdx.x & 63;
  const int wave  = threadIdx.x >> 6;
  const int sub   = lane >> 4;
  const int sl    = lane & 15;

  for (int k = threadIdx.x; k < D2; k += 256) sagg[k] = 0.0f;
  __syncthreads();

  const float4 g0  = *reinterpret_cast<const float4*>(g1 + sl * 8);
  const float4 g4  = *reinterpret_cast<const float4*>(g1 + sl * 8 + 4);
  const float4 t0  = *reinterpret_cast<const float4*>(b1 + sl * 8);
  const float4 t4  = *reinterpret_cast<const float4*>(b1 + sl * 8 + 4);
  const float bs0 = t0.x + t0.y + t0.z + t0.w;
  const float bs1 = t4.x + t4.y + t4.z + t4.w;

  const float* xt  = x + (size_t)t * TOK * E_DIM;
  const int*   nit = node_idx + (size_t)t * N_NODE_C;
  const int d0 = sl * 2, d1 = sl * 2 + 1;
  const int rowbase = chunk * 128 + wave * 32;  // 128 rows/WG, 32/wave

#pragma unroll
  for (int b = 0; b < 2; ++b)
    ln_scatter_batch(xt, nit, W32, sagg, rowbase, b * 4, sub, sl, g0, g4, bs0, bs1, d0, d1);

  __syncthreads();
  float* aggt = Agg + (size_t)t * D2;
  for (int k = threadIdx.x; k < D2; k += 256) atomicAdd(&aggt[k], sagg[k]);
}

__global__ __launch_bounds__(256) void final_ln_kernel_fb(
    const float* __restrict__ Agg, const float* __restrict__ g2,
    const float* __restrict__ b2, float* __restrict__ out) {
  const float scale = 1.0f / (4.0f * (float)MAX_LEN_C);
  __shared__ float red[16];
  const int t   = blockIdx.x;
  const int tid = threadIdx.x;
  float y[8];
  float s = 0.0f, ss = 0.0f;
#pragma unroll
  for (int k = 0; k < 8; ++k) {
    float v = Agg[(size_t)t * D2 + tid * 8 + k] * scale;
    y[k] = v; s += v; ss += v * v;
  }
#pragma unroll
  for (int m = 1; m < 64; m <<= 1) { s += __shfl_xor(s, m); ss += __shfl_xor(ss, m); }
  const int w = tid >> 6, ln = tid & 63;
  if (ln == 0) { red[w] = s; red[8 + w] = ss; }
  __syncthreads();
  float ts  = red[0] + red[1] + red[2] + red[3];
  float tss = red[8] + red[9] + red[10] + red[11];
  float mu   = ts * (1.0f / D2);
  float var  = tss * (1.0f / D2) - mu * mu;
  float rstd = rsqrtf(var + EPS_F);
#pragma unroll
  for (int k = 0; k < 8; ++k) {
    int idx = tid * 8 + k;
    out[(size_t)t * D2 + idx] = (y[k] - mu) * rstd * g2[idx] + b2[idx];
  }
}

extern "C" void kernel_launch(void* const* d_in, const int* in_sizes, int n_in,
                              void* d_out, int out_size, void* d_ws, size_t ws_size,
                              hipStream_t stream) {
  const float* x     = (const float*)d_in[0];
  const float* ln1_g = (const float*)d_in[1];
  const float* ln1_b = (const float*)d_in[2];
  const float* ln2_g = (const float*)d_in[3];
  const float* ln2_b = (const float*)d_in[4];
  const int* node_idx = (const int*)d_in[5];
  const int* sidx     = (const int*)d_in[6];
  float* out = (float*)d_out;

  unsigned char* ws = (unsigned char*)d_ws;
  unsigned* W8w = (unsigned*)ws;
  float* Agg = (float*)(ws + AGG_OFF);
  float* P   = (float*)(ws + P_OFF);

  // Deterministic host-side co-residency check (pure host API, capture-safe).
  int maxActive = 0;
  hipError_t occ = hipOccupancyMaxActiveBlocksPerMultiprocessor(
      &maxActive, (const void*)mega_kernel, BLK_C, 0);
  bool coop = (occ == hipSuccess) && (maxActive * 256 >= GRID_C * 2);  // 2x margin

  if (coop) {
    void* args[] = {(void*)&x, (void*)&ln1_g, (void*)&ln1_b, (void*)&node_idx,
                    (void*)&sidx, (void*)&ln2_g, (void*)&ln2_b,
                    (void*)&W8w, (void*)&P, (void*)&out};
    hipError_t e = hipLaunchCooperativeKernel((void*)mega_kernel, dim3(GRID_C),
                                              dim3(BLK_C), args, 0, stream);
    if (e == hipSuccess) return;
  }

  // Fallback: R8-proven 4-dispatch pipeline.
  hipMemsetAsync(ws, 0, ZERO_BYTES, stream);
  build_w8_kernel<<<COMP_LEN_C * 4, 256, 0, stream>>>(sidx, W8w);
  fused_ln_scatter_fb<<<T_DIM * 64, 256, 0, stream>>>(x, ln1_g, ln1_b, node_idx,
                                                      (const unsigned*)W8w, Agg);
  final_ln_kernel_fb<<<T_DIM, 256, 0, stream>>>(Agg, ln2_g, ln2_b, out);
}